// Round 7
// baseline (140.207 us; speedup 1.0000x reference)
//
#include <hip/hip_runtime.h>
#include <hip/hip_bf16.h>
#include <math.h>

#define BSZ 4096
#define D 128
#define NCLS 64
#define MARGIN_F 1.0f
#define LOSS_BLOCKS 256

typedef short bf16x8 __attribute__((ext_vector_type(8)));
typedef float f32x4  __attribute__((ext_vector_type(4)));

// ---- all scratch in device globals: no d_ws usage, graph-safe, re-inited every call ----
__device__ __align__(16) unsigned short g_Xbf[BSZ * D];   // 1 MB bf16 copy of X (L2-resident)
__device__ float g_mag[BSZ];
__device__ float g_row_neg[BSZ];
__device__ float g_acc;
__device__ int   g_hist[NCLS];
__device__ int   g_offs[NCLS];
__device__ int   g_counter;
__device__ int   g_order[BSZ];
__device__ int   g_done;

__device__ __forceinline__ unsigned short f2bf(float x) {
    union { __hip_bfloat16 h; unsigned short u; } cv;
    cv.h = __float2bfloat16(x);     // HW RNE convert
    return cv.u;
}

// ---------------- cvt: f32 -> bf16 copy + f32 mags + row_neg zeroing ----------------
// 64 blocks x 256 threads; block owns 64 rows (2048 float4). Fully coalesced reads/writes.
// Lanes 0..31 of each 32-lane segment cover exactly one row per j, so a 5-step shfl_xor
// segmented reduce yields that row's |x|^2 with no atomics and no LDS.
__global__ __launch_bounds__(256) void cvt_kernel(const float* __restrict__ X) {
    const int tid = threadIdx.x, bid = blockIdx.x;
    const int base = bid * 2048;               // float4 index base (= row base*32)
    const float4* G = (const float4*)X + base;
    if (tid < 64) g_row_neg[bid * 64 + tid] = 0.0f;
#pragma unroll
    for (int j = 0; j < 8; ++j) {
        int idx = tid + j * 256;
        float4 v = G[idx];
        *(ushort4*)(g_Xbf + (size_t)(base + idx) * 4) =
            make_ushort4(f2bf(v.x), f2bf(v.y), f2bf(v.z), f2bf(v.w));
        float m = fmaf(v.x, v.x, fmaf(v.y, v.y, fmaf(v.z, v.z, v.w * v.w)));
        m += __shfl_xor(m, 1); m += __shfl_xor(m, 2); m += __shfl_xor(m, 4);
        m += __shfl_xor(m, 8); m += __shfl_xor(m, 16);
        if ((tid & 31) == 0) g_mag[(base + idx) >> 5] = m;
    }
}

// ---------------- prep: hist + scan + scatter + accumulator zeroing (1 block) ----------------
__global__ __launch_bounds__(1024) void prep_kernel(const int* __restrict__ T) {
    __shared__ int hw[16][NCLS];    // per-wave histograms: no cross-wave same-address contention
    __shared__ int cur[NCLS];
    const int tid = threadIdx.x;
    const int w = tid >> 6;
    if (tid == 0) { g_acc = 0.0f; g_done = 0; }
    hw[tid >> 6][tid & 63] = 0;     // 16*64 == 1024
    __syncthreads();
    int lab[4];
#pragma unroll
    for (int j = 0; j < 4; ++j) lab[j] = T[tid + j * 1024];
#pragma unroll
    for (int j = 0; j < 4; ++j) atomicAdd(&hw[w][lab[j]], 1);
    __syncthreads();
    if (tid < 64) {                 // wave 0: combine + scan + pair counter
        int n = 0;
#pragma unroll
        for (int w2 = 0; w2 < 16; ++w2) n += hw[w2][tid];
        int x = n;
#pragma unroll
        for (int off = 1; off < 64; off <<= 1) {
            int y = __shfl_up(x, off);
            if (tid >= off) x += y;
        }
        g_offs[tid] = x - n; g_hist[tid] = n; cur[tid] = x - n;
        int pc = n * (n - 1) / 2;
#pragma unroll
        for (int off = 32; off > 0; off >>= 1) pc += __shfl_down(pc, off);
        if (tid == 0) g_counter = pc;
    }
    __syncthreads();
#pragma unroll
    for (int j = 0; j < 4; ++j) {
        int p = atomicAdd(&cur[lab[j]], 1);
        g_order[p] = tid + j * 1024;
    }
}

// ---------------- row_neg: LDS-free, barrier-free bf16 MFMA Gram + masked exp sums ----------
// Grid = 2080 upper-triangle 64x64 tiles. Each wave owns a 32x32 quadrant (2x2 16x16 frags).
// Fragments gathered directly from the L2-resident g_Xbf (16B/lane dwordx4); A and B use
// IDENTICAL lane patterns so any k-permutation in the HW frag layout cancels in A*A^T.
// C/D layout: col=lane&15, row=(lane>>4)*4+reg (HW-validated rounds 5-6).
// f32 mags are safe: only same-label entries can have d2~0 and those are label-masked.
__global__ __launch_bounds__(256) void rowneg_kernel(const int* __restrict__ T) {
    // triangular decode: cum(r) = r*(129-r)/2 (exact in int)
    const int p = blockIdx.x;
    int bi = (int)((129.0f - sqrtf(16641.0f - 8.0f * (float)p)) * 0.5f);
    bi = max(0, min(63, bi));
    while (bi * (129 - bi) / 2 > p) --bi;
    while (bi < 63 && (bi + 1) * (129 - (bi + 1)) / 2 <= p) ++bi;
    const int bj = bi + (p - bi * (129 - bi) / 2);

    const int tid = threadIdx.x;
    const int biBase = bi * 64, bjBase = bj * 64;
    const int l = tid & 63, w = tid >> 6;
    const int wr = w >> 1, wc = w & 1;
    const int l15 = l & 15, l4 = l >> 4;

    f32x4 acc[2][2];
#pragma unroll
    for (int mi = 0; mi < 2; ++mi)
#pragma unroll
        for (int ni = 0; ni < 2; ++ni)
            acc[mi][ni] = (f32x4){0.0f, 0.0f, 0.0f, 0.0f};

    const int arow0 = biBase + wr * 32 + l15;        // +mi*16
    const int brow0 = bjBase + wc * 32 + l15;        // +ni*16
#pragma unroll
    for (int ks = 0; ks < 4; ++ks) {
        const int koff = (ks * 4 + l4) * 8;          // bf16 element offset of this 16B chunk
        bf16x8 afr[2], bfr[2];
#pragma unroll
        for (int mi = 0; mi < 2; ++mi)
            afr[mi] = *(const bf16x8*)(g_Xbf + (size_t)(arow0 + mi * 16) * D + koff);
#pragma unroll
        for (int ni = 0; ni < 2; ++ni)
            bfr[ni] = *(const bf16x8*)(g_Xbf + (size_t)(brow0 + ni * 16) * D + koff);
#pragma unroll
        for (int mi = 0; mi < 2; ++mi)
#pragma unroll
            for (int ni = 0; ni < 2; ++ni)
                acc[mi][ni] = __builtin_amdgcn_mfma_f32_16x16x32_bf16(
                    afr[mi], bfr[ni], acc[mi][ni], 0, 0, 0);
    }

    // per-lane row/col metadata (L1-resident reads)
    float magr[2][4], magc[2];
    int   labr[2][4], labc[2];
#pragma unroll
    for (int mi = 0; mi < 2; ++mi)
#pragma unroll
        for (int j = 0; j < 4; ++j) {
            int r = biBase + wr * 32 + mi * 16 + l4 * 4 + j;
            magr[mi][j] = g_mag[r]; labr[mi][j] = T[r];
        }
#pragma unroll
    for (int ni = 0; ni < 2; ++ni) {
        int c2 = bjBase + wc * 32 + ni * 16 + l15;
        magc[ni] = g_mag[c2]; labc[ni] = T[c2];
    }

    // masked exp; row partials rp, col partials cp
    float rp[2][4] = {{0.f,0.f,0.f,0.f},{0.f,0.f,0.f,0.f}};
    float cp[2] = {0.f, 0.f};
#pragma unroll
    for (int mi = 0; mi < 2; ++mi)
#pragma unroll
        for (int ni = 0; ni < 2; ++ni)
#pragma unroll
            for (int j = 0; j < 4; ++j) {
                float s = acc[mi][ni][j];
                if (labr[mi][j] != labc[ni]) {
                    float d2 = fmaxf(magr[mi][j] + magc[ni] - 2.0f * s, 0.0f);
                    float t = __expf(MARGIN_F - sqrtf(d2));
                    rp[mi][j] += t;
                    cp[ni] += t;
                }
            }

    // row sums: butterfly over the 16 l15 lanes of each group
#pragma unroll
    for (int mi = 0; mi < 2; ++mi)
#pragma unroll
        for (int j = 0; j < 4; ++j) {
            float v = rp[mi][j];
            v += __shfl_xor(v, 1); v += __shfl_xor(v, 2);
            v += __shfl_xor(v, 4); v += __shfl_xor(v, 8);
            rp[mi][j] = v;
        }
    if (l15 == 0) {
#pragma unroll
        for (int mi = 0; mi < 2; ++mi)
#pragma unroll
            for (int j = 0; j < 4; ++j)
                atomicAdd(&g_row_neg[biBase + wr * 32 + mi * 16 + l4 * 4 + j], rp[mi][j]);
    }
    // col sums (symmetric contribution): butterfly over the 4 l4 groups
    if (bj > bi) {
#pragma unroll
        for (int ni = 0; ni < 2; ++ni) {
            float v = cp[ni];
            v += __shfl_xor(v, 16); v += __shfl_xor(v, 32);
            if (l4 == 0)
                atomicAdd(&g_row_neg[bjBase + wc * 32 + ni * 16 + l15], v);
        }
    }
}

// ---------------- positive-pair hinge loss + fused final division ----------------
__global__ __launch_bounds__(256) void loss_kernel(const float* __restrict__ X,
                                                   float* __restrict__ out) {
    const int c = blockIdx.x;
    const int n = g_hist[c];
    const int base = g_offs[c];
    const long long P = (long long)n * (n - 1) / 2;
    float lacc = 0.0f;

    for (long long p = threadIdx.x + (long long)blockIdx.y * 256; p < P; p += 1024) {
        // decode (a,b), a<b, from linear upper-triangular index p
        float nf = (float)n;
        float pf = (float)p;
        int a = (int)((nf - 0.5f) - sqrtf((nf - 0.5f) * (nf - 0.5f) - 2.0f * pf));
        if (a < 0) a = 0;
        if (a > n - 2) a = n - 2;
        auto cum = [&](int aa) -> long long {
            return (long long)aa * (n - 1) - (long long)aa * (aa - 1) / 2;
        };
        while (cum(a + 1) <= p) ++a;
        while (cum(a) > p) --a;
        int b = (int)(p - cum(a)) + a + 1;

        int ia = g_order[base + a], ib = g_order[base + b];
        const float4* xa = (const float4*)(X + (size_t)ia * D);
        const float4* xb = (const float4*)(X + (size_t)ib * D);
        float d2 = 0.0f;
#pragma unroll
        for (int k = 0; k < D / 4; ++k) {
            float4 u = xa[k]; float4 v = xb[k];
            float dx = u.x - v.x, dy = u.y - v.y, dz = u.z - v.z, dw = u.w - v.w;
            d2 = fmaf(dx, dx, d2); d2 = fmaf(dy, dy, d2);
            d2 = fmaf(dz, dz, d2); d2 = fmaf(dw, dw, d2);
        }
        float dist = sqrtf(d2);
        float ln = logf(g_row_neg[ia] + g_row_neg[ib]);
        float h = fmaxf(ln + dist, 0.0f);
        lacc = fmaf(h, h, lacc);
    }

    for (int off = 32; off > 0; off >>= 1) lacc += __shfl_down(lacc, off);
    __shared__ float ws[4];
    int lane = threadIdx.x & 63, w = threadIdx.x >> 6;
    if (lane == 0) ws[w] = lacc;
    __syncthreads();
    if (threadIdx.x == 0) {
        atomicAdd(&g_acc, ws[0] + ws[1] + ws[2] + ws[3]);
        __threadfence();
        int d = atomicAdd(&g_done, 1);
        if (d == LOSS_BLOCKS - 1) {            // last block: fused final division
            __threadfence();
            float total = atomicAdd(&g_acc, 0.0f);   // device-scope coherent read
            out[0] = total / (2.0f * (float)g_counter);
        }
    }
}

extern "C" void kernel_launch(void* const* d_in, const int* in_sizes, int n_in,
                              void* d_out, int out_size, void* d_ws, size_t ws_size,
                              hipStream_t stream) {
    const float* X = (const float*)d_in[0];
    const int* T = (const int*)d_in[1];
    float* out = (float*)d_out;
    (void)d_ws; (void)ws_size;

    cvt_kernel<<<dim3(64), dim3(256), 0, stream>>>(X);
    prep_kernel<<<dim3(1), dim3(1024), 0, stream>>>(T);
    rowneg_kernel<<<dim3(2080), dim3(256), 0, stream>>>(T);
    loss_kernel<<<dim3(64, 4), dim3(256), 0, stream>>>(X, out);
}

// Round 11
// 131.665 us; speedup vs baseline: 1.0649x; 1.0649x over previous
//
#include <hip/hip_runtime.h>
#include <hip/hip_bf16.h>
#include <math.h>

#define BSZ 4096
#define D 128
#define NCLS 64
#define MARGIN_F 1.0f
#define LOSS_BLOCKS 256

typedef short bf16x8 __attribute__((ext_vector_type(8)));
typedef float f32x4  __attribute__((ext_vector_type(4)));

// ---- all scratch in device globals: no d_ws usage, graph-safe, re-inited every call ----
__device__ float g_row_neg[BSZ];
__device__ float g_acc;
__device__ int   g_hist[NCLS];
__device__ int   g_offs[NCLS];
__device__ int   g_counter;
__device__ int   g_order[BSZ];
__device__ int   g_done;

__device__ __forceinline__ unsigned short f2bf(float x) {
    union { __hip_bfloat16 h; unsigned short u; } cv;
    cv.h = __float2bfloat16(x);     // HW RNE convert
    return cv.u;
}

// ---------------- prep: zero accumulators + hist + scan + scatter (1 block) ----------------
__global__ __launch_bounds__(1024) void prep_kernel(const int* __restrict__ T) {
    __shared__ int hw[16][NCLS];    // per-wave histograms: no cross-wave same-address contention
    __shared__ int cur[NCLS];
    const int tid = threadIdx.x;
    const int w = tid >> 6;
#pragma unroll
    for (int j = 0; j < 4; ++j) g_row_neg[tid + j * 1024] = 0.0f;
    if (tid == 0) { g_acc = 0.0f; g_done = 0; }
    hw[tid >> 6][tid & 63] = 0;     // 16*64 == 1024
    __syncthreads();
    int lab[4];
#pragma unroll
    for (int j = 0; j < 4; ++j) lab[j] = T[tid + j * 1024];
#pragma unroll
    for (int j = 0; j < 4; ++j) atomicAdd(&hw[w][lab[j]], 1);
    __syncthreads();
    if (tid < 64) {                 // wave 0: combine + scan + pair counter
        int n = 0;
#pragma unroll
        for (int w2 = 0; w2 < 16; ++w2) n += hw[w2][tid];
        int x = n;
#pragma unroll
        for (int off = 1; off < 64; off <<= 1) {
            int y = __shfl_up(x, off);
            if (tid >= off) x += y;
        }
        g_offs[tid] = x - n; g_hist[tid] = n; cur[tid] = x - n;
        int pc = n * (n - 1) / 2;
#pragma unroll
        for (int off = 32; off > 0; off >>= 1) pc += __shfl_down(pc, off);
        if (tid == 0) g_counter = pc;
    }
    __syncthreads();
#pragma unroll
    for (int j = 0; j < 4; ++j) {
        int p = atomicAdd(&cur[lab[j]], 1);
        g_order[p] = tid + j * 1024;
    }
}

// ---------------- row_neg: LDS-staged bf16 MFMA symmetric Gram + masked exp sums ----------
// Grid = 2080 upper-triangle 64x64 tiles (triangular decode). Staging is the R5 proven
// pattern: linear coalesced float4 reads (1KB contiguous per wave-instruction), f32->bf16,
// swizzled LDS writes ([64][128] bf16 row-major, 16B chunk ^ (row&7)); f32 row mags fused
// into staging via 32-lane segmented shuffle (each 32-lane group covers exactly one row).
// MFMA: 4 waves x 2x2 16x16x32 frags; A/B frags use IDENTICAL lane patterns so any
// k-permutation cancels in A*A^T. C/D layout col=lane&15, row=(lane>>4)*4+reg (HW-validated
// rounds 5-7). Epilogue: masked exp, shuffle butterfly reductions, direct global atomics.
__global__ __launch_bounds__(256) void rowneg_kernel(const float* __restrict__ X,
                                                     const int* __restrict__ T) {
    // triangular decode: cum(r) = r*(129-r)/2 (exact in int)
    const int p = blockIdx.x;
    int bi = (int)((129.0f - sqrtf(16641.0f - 8.0f * (float)p)) * 0.5f);
    bi = max(0, min(63, bi));
    while (bi * (129 - bi) / 2 > p) --bi;
    while (bi < 63 && (bi + 1) * (129 - (bi + 1)) / 2 <= p) ++bi;
    const int bj = bi + (p - bi * (129 - bi) / 2);

    __shared__ __align__(16) unsigned short Ab[64 * 128];  // 16 KB
    __shared__ __align__(16) unsigned short Bb[64 * 128];  // 16 KB
    __shared__ float magA[64], magB[64];
    __shared__ int   labA[64], labB[64];

    const int tid = threadIdx.x;
    const int biBase = bi * 64, bjBase = bj * 64;

    // ---- stage A,B tiles (coalesced) + fused f32 mags (segmented shuffle) ----
    {
        const float4* GA = (const float4*)(X + (size_t)biBase * D);
        const float4* GB = (const float4*)(X + (size_t)bjBase * D);
#pragma unroll
        for (int j = 0; j < 8; ++j) {
            int idx = tid + j * 256;            // linear float4 index 0..2047 (coalesced)
            int row = idx >> 5, f4 = idx & 31;
            int c = f4 >> 1, hh = f4 & 1;
            int byteoff = row * 256 + ((c ^ (row & 7)) << 4) + (hh << 3);
            float4 a = GA[idx];
            *(ushort4*)((char*)Ab + byteoff) = make_ushort4(f2bf(a.x), f2bf(a.y), f2bf(a.z), f2bf(a.w));
            float ma = fmaf(a.x, a.x, fmaf(a.y, a.y, fmaf(a.z, a.z, a.w * a.w)));
            float4 b = GB[idx];
            *(ushort4*)((char*)Bb + byteoff) = make_ushort4(f2bf(b.x), f2bf(b.y), f2bf(b.z), f2bf(b.w));
            float mb = fmaf(b.x, b.x, fmaf(b.y, b.y, fmaf(b.z, b.z, b.w * b.w)));
            // 32-lane segmented reduce: each 32-lane group covers exactly row `idx>>5`
            ma += __shfl_xor(ma, 1); ma += __shfl_xor(ma, 2); ma += __shfl_xor(ma, 4);
            ma += __shfl_xor(ma, 8); ma += __shfl_xor(ma, 16);
            mb += __shfl_xor(mb, 1); mb += __shfl_xor(mb, 2); mb += __shfl_xor(mb, 4);
            mb += __shfl_xor(mb, 8); mb += __shfl_xor(mb, 16);
            if ((tid & 31) == 0) { magA[row] = ma; magB[row] = mb; }
        }
    }
    if (tid < 64)       labA[tid] = T[biBase + tid];
    else if (tid < 128) labB[tid - 64] = T[bjBase + tid - 64];
    __syncthreads();

    // ---- MFMA: each wave computes a 32x32 quadrant (2x2 fragments), K=128 in 4 steps ----
    const int l = tid & 63, w = tid >> 6;
    const int wr = w >> 1, wc = w & 1;
    const int l15 = l & 15, l4 = l >> 4;

    f32x4 acc[2][2];
#pragma unroll
    for (int mi = 0; mi < 2; ++mi)
#pragma unroll
        for (int ni = 0; ni < 2; ++ni)
            acc[mi][ni] = (f32x4){0.0f, 0.0f, 0.0f, 0.0f};

#pragma unroll
    for (int ks = 0; ks < 4; ++ks) {
        int cch = ks * 4 + l4;                  // 16B chunk index = k-offset/8
        bf16x8 afr[2], bfr[2];
#pragma unroll
        for (int mi = 0; mi < 2; ++mi) {
            int row = wr * 32 + mi * 16 + l15;
            afr[mi] = *(const bf16x8*)((const char*)Ab + row * 256 + ((cch ^ (row & 7)) << 4));
        }
#pragma unroll
        for (int ni = 0; ni < 2; ++ni) {
            int row = wc * 32 + ni * 16 + l15;
            bfr[ni] = *(const bf16x8*)((const char*)Bb + row * 256 + ((cch ^ (row & 7)) << 4));
        }
#pragma unroll
        for (int mi = 0; mi < 2; ++mi)
#pragma unroll
            for (int ni = 0; ni < 2; ++ni)
                acc[mi][ni] = __builtin_amdgcn_mfma_f32_16x16x32_bf16(
                    afr[mi], bfr[ni], acc[mi][ni], 0, 0, 0);
    }

    // ---- epilogue: masked exp; shuffle-reduced row/col sums -> direct global atomics ----
    float rp[2][4] = {{0.f,0.f,0.f,0.f},{0.f,0.f,0.f,0.f}};
    float cp[2] = {0.f, 0.f};
#pragma unroll
    for (int mi = 0; mi < 2; ++mi)
#pragma unroll
        for (int ni = 0; ni < 2; ++ni)
#pragma unroll
            for (int j = 0; j < 4; ++j) {
                int rl = wr * 32 + mi * 16 + l4 * 4 + j;   // local row
                int cl = wc * 32 + ni * 16 + l15;          // local col
                float s = acc[mi][ni][j];
                if (labA[rl] != labB[cl]) {
                    float d2 = fmaxf(magA[rl] + magB[cl] - 2.0f * s, 0.0f);
                    float t = __expf(MARGIN_F - sqrtf(d2));
                    rp[mi][j] += t;
                    cp[ni] += t;
                }
            }

    // row sums: butterfly over the 16 l15 lanes of each group
#pragma unroll
    for (int mi = 0; mi < 2; ++mi)
#pragma unroll
        for (int j = 0; j < 4; ++j) {
            float v = rp[mi][j];
            v += __shfl_xor(v, 1); v += __shfl_xor(v, 2);
            v += __shfl_xor(v, 4); v += __shfl_xor(v, 8);
            rp[mi][j] = v;
        }
    if (l15 == 0) {
#pragma unroll
        for (int mi = 0; mi < 2; ++mi)
#pragma unroll
            for (int j = 0; j < 4; ++j)
                atomicAdd(&g_row_neg[biBase + wr * 32 + mi * 16 + l4 * 4 + j], rp[mi][j]);
    }
    // col sums (symmetric contribution): butterfly over the 4 l4 groups
    if (bj > bi) {
#pragma unroll
        for (int ni = 0; ni < 2; ++ni) {
            float v = cp[ni];
            v += __shfl_xor(v, 16); v += __shfl_xor(v, 32);
            if (l4 == 0)
                atomicAdd(&g_row_neg[bjBase + wc * 32 + ni * 16 + l15], v);
        }
    }
}

// ---------------- positive-pair hinge loss + fused final division ----------------
__global__ __launch_bounds__(256) void loss_kernel(const float* __restrict__ X,
                                                   float* __restrict__ out) {
    const int c = blockIdx.x;
    const int n = g_hist[c];
    const int base = g_offs[c];
    const long long P = (long long)n * (n - 1) / 2;
    float lacc = 0.0f;

    for (long long p = threadIdx.x + (long long)blockIdx.y * 256; p < P; p += 1024) {
        // decode (a,b), a<b, from linear upper-triangular index p
        float nf = (float)n;
        float pf = (float)p;
        int a = (int)((nf - 0.5f) - sqrtf((nf - 0.5f) * (nf - 0.5f) - 2.0f * pf));
        if (a < 0) a = 0;
        if (a > n - 2) a = n - 2;
        auto cum = [&](int aa) -> long long {
            return (long long)aa * (n - 1) - (long long)aa * (aa - 1) / 2;
        };
        while (cum(a + 1) <= p) ++a;
        while (cum(a) > p) --a;
        int b = (int)(p - cum(a)) + a + 1;

        int ia = g_order[base + a], ib = g_order[base + b];
        const float4* xa = (const float4*)(X + (size_t)ia * D);
        const float4* xb = (const float4*)(X + (size_t)ib * D);
        float d2 = 0.0f;
#pragma unroll
        for (int k = 0; k < D / 4; ++k) {
            float4 u = xa[k]; float4 v = xb[k];
            float dx = u.x - v.x, dy = u.y - v.y, dz = u.z - v.z, dw = u.w - v.w;
            d2 = fmaf(dx, dx, d2); d2 = fmaf(dy, dy, d2);
            d2 = fmaf(dz, dz, d2); d2 = fmaf(dw, dw, d2);
        }
        float dist = sqrtf(d2);
        float ln = logf(g_row_neg[ia] + g_row_neg[ib]);
        float h = fmaxf(ln + dist, 0.0f);
        lacc = fmaf(h, h, lacc);
    }

    for (int off = 32; off > 0; off >>= 1) lacc += __shfl_down(lacc, off);
    __shared__ float ws[4];
    int lane = threadIdx.x & 63, w = threadIdx.x >> 6;
    if (lane == 0) ws[w] = lacc;
    __syncthreads();
    if (threadIdx.x == 0) {
        atomicAdd(&g_acc, ws[0] + ws[1] + ws[2] + ws[3]);
        __threadfence();
        int d = atomicAdd(&g_done, 1);
        if (d == LOSS_BLOCKS - 1) {            // last block: fused final division
            __threadfence();
            float total = atomicAdd(&g_acc, 0.0f);   // device-scope coherent read
            out[0] = total / (2.0f * (float)g_counter);
        }
    }
}

extern "C" void kernel_launch(void* const* d_in, const int* in_sizes, int n_in,
                              void* d_out, int out_size, void* d_ws, size_t ws_size,
                              hipStream_t stream) {
    const float* X = (const float*)d_in[0];
    const int* T = (const int*)d_in[1];
    float* out = (float*)d_out;
    (void)d_ws; (void)ws_size;

    prep_kernel<<<dim3(1), dim3(1024), 0, stream>>>(T);
    rowneg_kernel<<<dim3(2080), dim3(256), 0, stream>>>(X, T);
    loss_kernel<<<dim3(64, 4), dim3(256), 0, stream>>>(X, out);
}

// Round 15
// 128.850 us; speedup vs baseline: 1.0881x; 1.0218x over previous
//
#include <hip/hip_runtime.h>
#include <hip/hip_bf16.h>
#include <math.h>

#define BSZ 4096
#define D 128
#define NCLS 64
#define MARGIN_F 1.0f
#define LOSS_BLOCKS 256
#define NRT 32            // 4096/128 row-tiles
#define NBLK 528          // NRT*(NRT+1)/2 upper-triangle tiles

typedef short bf16x8 __attribute__((ext_vector_type(8)));
typedef float f32x4  __attribute__((ext_vector_type(4)));

// ---- all scratch in device globals: no d_ws usage, graph-safe, re-inited every call ----
__device__ __align__(16) unsigned short g_Xbf[BSZ * D];   // 1 MB bf16 copy of X
__device__ float g_mag[BSZ];
__device__ float g_row_neg[BSZ];
__device__ float g_acc;
__device__ int   g_hist[NCLS];
__device__ int   g_offs[NCLS];
__device__ int   g_counter;
__device__ int   g_order[BSZ];
__device__ int   g_done;

__device__ __forceinline__ unsigned short f2bf(float x) {
    union { __hip_bfloat16 h; unsigned short u; } cv;
    cv.h = __float2bfloat16(x);     // HW RNE convert
    return cv.u;
}

// ------- setup: blocks 0..63 convert X->bf16 + mags + zero row_neg; block 64 = prep -------
__global__ __launch_bounds__(512) void setup_kernel(const float* __restrict__ X,
                                                    const int* __restrict__ T) {
    const int tid = threadIdx.x, bid = blockIdx.x;
    if (bid < 64) {
        const int base = bid * 2048;               // float4 index base (64 rows)
        const float4* G = (const float4*)X + base;
        if (tid < 64) g_row_neg[bid * 64 + tid] = 0.0f;
#pragma unroll
        for (int it = 0; it < 4; ++it) {
            int idx = tid + it * 512;
            float4 v = G[idx];
            *(ushort4*)(g_Xbf + (size_t)(base + idx) * 4) =
                make_ushort4(f2bf(v.x), f2bf(v.y), f2bf(v.z), f2bf(v.w));
            float m = fmaf(v.x, v.x, fmaf(v.y, v.y, fmaf(v.z, v.z, v.w * v.w)));
            // 32-lane segmented reduce: each 32-lane half-wave covers one row
            m += __shfl_xor(m, 1); m += __shfl_xor(m, 2); m += __shfl_xor(m, 4);
            m += __shfl_xor(m, 8); m += __shfl_xor(m, 16);
            if ((tid & 31) == 0) g_mag[(base + idx) >> 5] = m;
        }
    } else {
        // prep: hist + scan + scatter (512 threads, 8 labels each)
        __shared__ int hw[8][NCLS];
        __shared__ int cur[NCLS];
        const int w = tid >> 6;
        if (tid == 0) { g_acc = 0.0f; g_done = 0; }
        hw[tid >> 6][tid & 63] = 0;     // 8*64 == 512
        __syncthreads();
        int lab[8];
#pragma unroll
        for (int j = 0; j < 8; ++j) lab[j] = T[tid + j * 512];
#pragma unroll
        for (int j = 0; j < 8; ++j) atomicAdd(&hw[w][lab[j]], 1);
        __syncthreads();
        if (tid < 64) {                 // wave 0: combine + scan + pair counter
            int n = 0;
#pragma unroll
            for (int w2 = 0; w2 < 8; ++w2) n += hw[w2][tid];
            int x = n;
#pragma unroll
            for (int off = 1; off < 64; off <<= 1) {
                int y = __shfl_up(x, off);
                if (tid >= off) x += y;
            }
            g_offs[tid] = x - n; g_hist[tid] = n; cur[tid] = x - n;
            int pc = n * (n - 1) / 2;
#pragma unroll
            for (int off = 32; off > 0; off >>= 1) pc += __shfl_down(pc, off);
            if (tid == 0) g_counter = pc;
        }
        __syncthreads();
#pragma unroll
        for (int j = 0; j < 8; ++j) {
            int p = atomicAdd(&cur[lab[j]], 1);
            g_order[p] = tid + j * 512;
        }
    }
}

// ------- row_neg: 128x128 bf16 MFMA tiles from g_Xbf + masked exp row/col sums -------
// 528 upper-triangle tiles, 512 threads (8 waves, 2x4 wave grid; each wave 64x32 quadrant =
// 4x2 16x16 frags x 4 K-steps = 32 MFMAs). LDS [128][128] bf16, swizzle chunk ^= (row&15)
// (bijective; read pattern 2-way max banks). A/B frags share lane pattern (ra&15 == rb&15
// == l15) so the k-permutation cancels in A*A^T (numerically validated rounds 5/6/11).
// C/D layout col=lane&15, row=(lane>>4)*4+reg (HW-validated).
__global__ __launch_bounds__(512) void rowneg_kernel(const int* __restrict__ T) {
    // triangular decode: cum(r) = r*(65-r)/2
    const int p = blockIdx.x;
    int bi = (int)((65.0f - sqrtf(4225.0f - 8.0f * (float)p)) * 0.5f);
    bi = max(0, min(NRT - 1, bi));
    while (bi * (65 - bi) / 2 > p) --bi;
    while (bi < NRT - 1 && (bi + 1) * (65 - (bi + 1)) / 2 <= p) ++bi;
    const int bj = bi + (p - bi * (65 - bi) / 2);

    __shared__ __align__(16) unsigned short Ab[128 * 128];  // 32 KB
    __shared__ __align__(16) unsigned short Bb[128 * 128];  // 32 KB
    __shared__ float magA[128], magB[128];
    __shared__ int   labA[128], labB[128];

    const int tid = threadIdx.x;
    const int biBase = bi * 128, bjBase = bj * 128;

    // ---- stage A,B bf16 tiles: 4+4 hoisted 16B loads/thread, coalesced ----
    bf16x8 av[4], bv[4];
#pragma unroll
    for (int j = 0; j < 4; ++j) {
        int idx = tid + j * 512;                // 0..2047 chunk index
        int row = idx >> 4, c = idx & 15;
        av[j] = *(const bf16x8*)(g_Xbf + (size_t)(biBase + row) * D + c * 8);
        bv[j] = *(const bf16x8*)(g_Xbf + (size_t)(bjBase + row) * D + c * 8);
    }
    if (tid < 128)      { magA[tid] = g_mag[biBase + tid]; labA[tid] = T[biBase + tid]; }
    else if (tid < 256) { int u = tid - 128; magB[u] = g_mag[bjBase + u]; labB[u] = T[bjBase + u]; }
#pragma unroll
    for (int j = 0; j < 4; ++j) {
        int idx = tid + j * 512;
        int row = idx >> 4, c = idx & 15;
        int off = row * 256 + ((c ^ (row & 15)) << 4);
        *(bf16x8*)((char*)Ab + off) = av[j];
        *(bf16x8*)((char*)Bb + off) = bv[j];
    }
    __syncthreads();

    // ---- MFMA: wave (wr,wc) owns rows wr*64+mi*16, cols wc*32+ni*16 ----
    const int l = tid & 63, w = tid >> 6;
    const int wr = w >> 2, wc = w & 3;
    const int l15 = l & 15, l4 = l >> 4;

    f32x4 acc[4][2];
#pragma unroll
    for (int mi = 0; mi < 4; ++mi)
#pragma unroll
        for (int ni = 0; ni < 2; ++ni)
            acc[mi][ni] = (f32x4){0.0f, 0.0f, 0.0f, 0.0f};

#pragma unroll
    for (int ks = 0; ks < 4; ++ks) {
        int cch = ks * 4 + l4;                  // 16B chunk index = k/8
        bf16x8 afr[4], bfr[2];
#pragma unroll
        for (int mi = 0; mi < 4; ++mi) {
            int row = wr * 64 + mi * 16 + l15;
            afr[mi] = *(const bf16x8*)((const char*)Ab + row * 256 + ((cch ^ (row & 15)) << 4));
        }
#pragma unroll
        for (int ni = 0; ni < 2; ++ni) {
            int row = wc * 32 + ni * 16 + l15;
            bfr[ni] = *(const bf16x8*)((const char*)Bb + row * 256 + ((cch ^ (row & 15)) << 4));
        }
#pragma unroll
        for (int mi = 0; mi < 4; ++mi)
#pragma unroll
            for (int ni = 0; ni < 2; ++ni)
                acc[mi][ni] = __builtin_amdgcn_mfma_f32_16x16x32_bf16(
                    afr[mi], bfr[ni], acc[mi][ni], 0, 0, 0);
    }

    // ---- epilogue: masked exp; butterfly reductions; direct global atomics ----
    float rp[4][4];
#pragma unroll
    for (int mi = 0; mi < 4; ++mi)
#pragma unroll
        for (int j = 0; j < 4; ++j) rp[mi][j] = 0.0f;
    float cp[2] = {0.f, 0.f};
#pragma unroll
    for (int mi = 0; mi < 4; ++mi)
#pragma unroll
        for (int ni = 0; ni < 2; ++ni)
#pragma unroll
            for (int j = 0; j < 4; ++j) {
                int rl = wr * 64 + mi * 16 + l4 * 4 + j;   // local row
                int cl = wc * 32 + ni * 16 + l15;          // local col
                float s = acc[mi][ni][j];
                if (labA[rl] != labB[cl]) {
                    float d2 = fmaxf(magA[rl] + magB[cl] - 2.0f * s, 0.0f);
                    float t = __expf(MARGIN_F - sqrtf(d2));
                    rp[mi][j] += t;
                    cp[ni] += t;
                }
            }

    // row sums: butterfly over the 16 l15 lanes (covers both ni halves per-lane already)
#pragma unroll
    for (int mi = 0; mi < 4; ++mi)
#pragma unroll
        for (int j = 0; j < 4; ++j) {
            float v = rp[mi][j];
            v += __shfl_xor(v, 1); v += __shfl_xor(v, 2);
            v += __shfl_xor(v, 4); v += __shfl_xor(v, 8);
            rp[mi][j] = v;
        }
    if (l15 == 0) {
#pragma unroll
        for (int mi = 0; mi < 4; ++mi)
#pragma unroll
            for (int j = 0; j < 4; ++j)
                atomicAdd(&g_row_neg[biBase + wr * 64 + mi * 16 + l4 * 4 + j], rp[mi][j]);
    }
    // col sums (symmetric contribution): butterfly over the 4 l4 groups
    if (bj > bi) {
#pragma unroll
        for (int ni = 0; ni < 2; ++ni) {
            float v = cp[ni];
            v += __shfl_xor(v, 16); v += __shfl_xor(v, 32);
            if (l4 == 0)
                atomicAdd(&g_row_neg[bjBase + wc * 32 + ni * 16 + l15], v);
        }
    }
}

// ---------------- positive-pair hinge loss + fused final division ----------------
__global__ __launch_bounds__(256) void loss_kernel(const float* __restrict__ X,
                                                   float* __restrict__ out) {
    const int c = blockIdx.x;
    const int n = g_hist[c];
    const int base = g_offs[c];
    const long long P = (long long)n * (n - 1) / 2;
    float lacc = 0.0f;

    for (long long p = threadIdx.x + (long long)blockIdx.y * 256; p < P; p += 1024) {
        // decode (a,b), a<b, from linear upper-triangular index p
        float nf = (float)n;
        float pf = (float)p;
        int a = (int)((nf - 0.5f) - sqrtf((nf - 0.5f) * (nf - 0.5f) - 2.0f * pf));
        if (a < 0) a = 0;
        if (a > n - 2) a = n - 2;
        auto cum = [&](int aa) -> long long {
            return (long long)aa * (n - 1) - (long long)aa * (aa - 1) / 2;
        };
        while (cum(a + 1) <= p) ++a;
        while (cum(a) > p) --a;
        int b = (int)(p - cum(a)) + a + 1;

        int ia = g_order[base + a], ib = g_order[base + b];
        const float4* xa = (const float4*)(X + (size_t)ia * D);
        const float4* xb = (const float4*)(X + (size_t)ib * D);
        float d2 = 0.0f;
#pragma unroll
        for (int k = 0; k < D / 4; ++k) {
            float4 u = xa[k]; float4 v = xb[k];
            float dx = u.x - v.x, dy = u.y - v.y, dz = u.z - v.z, dw = u.w - v.w;
            d2 = fmaf(dx, dx, d2); d2 = fmaf(dy, dy, d2);
            d2 = fmaf(dz, dz, d2); d2 = fmaf(dw, dw, d2);
        }
        float dist = sqrtf(d2);
        float ln = logf(g_row_neg[ia] + g_row_neg[ib]);
        float h = fmaxf(ln + dist, 0.0f);
        lacc = fmaf(h, h, lacc);
    }

    for (int off = 32; off > 0; off >>= 1) lacc += __shfl_down(lacc, off);
    __shared__ float ws[4];
    int lane = threadIdx.x & 63, w = threadIdx.x >> 6;
    if (lane == 0) ws[w] = lacc;
    __syncthreads();
    if (threadIdx.x == 0) {
        atomicAdd(&g_acc, ws[0] + ws[1] + ws[2] + ws[3]);
        __threadfence();
        int d = atomicAdd(&g_done, 1);
        if (d == LOSS_BLOCKS - 1) {            // last block: fused final division
            __threadfence();
            float total = atomicAdd(&g_acc, 0.0f);   // device-scope coherent read
            out[0] = total / (2.0f * (float)g_counter);
        }
    }
}

extern "C" void kernel_launch(void* const* d_in, const int* in_sizes, int n_in,
                              void* d_out, int out_size, void* d_ws, size_t ws_size,
                              hipStream_t stream) {
    const float* X = (const float*)d_in[0];
    const int* T = (const int*)d_in[1];
    float* out = (float*)d_out;
    (void)d_ws; (void)ws_size;

    setup_kernel<<<dim3(65), dim3(512), 0, stream>>>(X, T);
    rowneg_kernel<<<dim3(NBLK), dim3(512), 0, stream>>>(T);
    loss_kernel<<<dim3(64, 4), dim3(256), 0, stream>>>(X, out);
}